// Round 6
// baseline (180.339 us; speedup 1.0000x reference)
//
#include <hip/hip_runtime.h>

// SinkhornAttention: b=4,h=8,t=8192,dh=64, BUCKETS=64, bucket size 128.
// k1: bucket sums -> x[bh][64][128]
// k3: fused sortnet (per-wave, redundant) + bucketed attention.
//     PROVEN round-2 MFMA dataflow: S^T = mfma(K_afrag, Q_bfrag);
//     P->bf16 via cvt_pk+permlane32_swap; O = mfma(P_afrag, VT_bfrag).
//     Softmax via FIXED shift M (exact by shift invariance; inputs are
//     N(0,1) -> logits2 sigma~0.5, max ~ +4 << M=12, overflow margin 25+ sigma),
//     so O is never rescaled mid-loop and no online-softmax domain hazards
//     exist. Per-q-row 1/lsum distributed in the epilogue via __shfl.

#define T_TOK 8192
// 512^-0.5 * log2(e): fold into Q so logits land in exp2 domain.
#define CQ (0.04419417382415922f * 1.4426950408889634f)
#define FIXED_M 12.0f

typedef __attribute__((ext_vector_type(16))) float f32x16;
typedef __attribute__((ext_vector_type(8))) short bf16x8;

__device__ __forceinline__ unsigned cvtpk(float lo, float hi) {
  unsigned r;
  asm("v_cvt_pk_bf16_f32 %0, %1, %2" : "=v"(r) : "v"(lo), "v"(hi));
  return r;
}
__device__ __forceinline__ float exp2v(float x) {
  float r;
  asm("v_exp_f32 %0, %1\n\ts_nop 0" : "=v"(r) : "v"(x));
  return r;
}

// ---------------- Kernel 1: bucket summaries ----------------
__global__ __launch_bounds__(128) void k1_sums(const float* __restrict__ q,
                                               const float* __restrict__ k,
                                               float* __restrict__ x) {
  int G = blockIdx.x;
  int bhi = G >> 6, u = G & 63;
  int tid = threadIdx.x;
  const float* src = (tid < 64) ? q : k;
  int d = tid & 63;
  const float* p = src + ((size_t)bhi * T_TOK + (size_t)u * 128) * 64 + d;
  float s = 0.f;
  #pragma unroll 8
  for (int t = 0; t < 128; ++t) s += p[(size_t)t * 64];
  x[(size_t)G * 128 + tid] = s;
}

// ---------------- Kernel 3: fused sortnet + bucketed attention ----------------
// grid 2048, block 256 (4 waves). Wave w owns Q rows [32w,32w+32).
// LDS 32KB: VT = V_cat^T bf16 [64 d][256 tok], addr = d*512 + ((2*tok)^((d&31)<<4)).
//   toks 0..127 = ru*V[vu], toks 128..255 = V[u].
__global__ __launch_bounds__(256, 4) void k3_attn(
    const float* __restrict__ q, const float* __restrict__ k,
    const float* __restrict__ v, const float* __restrict__ x,
    const float* __restrict__ W, float* __restrict__ out) {
  __shared__ unsigned char smem[32768];

  int L = blockIdx.x;
  int G = ((L & 7) << 8) | (L >> 3);  // XCD swizzle (2048 % 8 == 0)
  int bhi = G >> 6, u = G & 63;
  int tid = threadIdx.x;
  int l = tid & 63;
  int w = tid >> 6;
  int lhi = l >> 5;
  int ln = l & 31;
  int hh = bhi & 7;

  const float* kb = k + (size_t)bhi * (T_TOK * 64);
  const float* vb = v + (size_t)bhi * (T_TOK * 64);

  // ---- stage V-own -> VT toks 128..255 (no dependency on sortnet) ----
  int tp = tid >> 2;  // 0..63 token-pair
  {
    const float* s0 = vb + ((size_t)(u * 128 + 2 * tp)) * 64 + (tid & 3) * 4;
    #pragma unroll
    for (int i = 0; i < 4; ++i) {
      int dq = (tid & 3) + 4 * i;
      float4 va = *reinterpret_cast<const float4*>(s0 + i * 16);
      float4 vc = *reinterpret_cast<const float4*>(s0 + i * 16 + 64);
      int t2 = 256 + 4 * tp;  // 2*(128 + 2*tp)
      const float* fa = (const float*)&va;
      const float* fc = (const float*)&vc;
      #pragma unroll
      for (int jj = 0; jj < 4; ++jj) {
        int d = dq * 4 + jj;
        int addr = d * 512 + (t2 ^ ((d & 31) << 4));
        *reinterpret_cast<unsigned*>(smem + addr) = cvtpk(fa[jj], fc[jj]);
      }
    }
  }

  // ---- sortnet, per-wave redundant: lane = candidate bucket v ----
  // fmaf over kk ascending: bitwise-identical to the validated k2 chain.
  const float* xrow = x + (size_t)bhi * 8192 + u * 128;
  const float* wcol = W + (size_t)hh * 8192 + l;
  float a = 0.f;
  #pragma unroll 8
  for (int kk = 0; kk < 128; ++kk) a = fmaf(xrow[kk], wcol[(size_t)kk * 64], a);
  a = fmaxf(a, 0.f);
  float bv = a; int bi = l;
  #pragma unroll
  for (int off = 1; off < 64; off <<= 1) {
    float ov = __shfl_xor(bv, off, 64);
    int oi = __shfl_xor(bi, off, 64);
    if (ov > bv || (ov == bv && oi < bi)) { bv = ov; bi = oi; }
  }
  float e = __expf(a - bv);
  #pragma unroll
  for (int off = 1; off < 64; off <<= 1) e += __shfl_xor(e, off, 64);
  int vu = bi;          // identical across wave
  float ru = 1.f / e;   // softmax value at argmax

  // ---- stage V-vu (scaled by ru) -> VT toks 0..127 ----
  {
    const float* s0 = vb + ((size_t)(vu * 128 + 2 * tp)) * 64 + (tid & 3) * 4;
    #pragma unroll
    for (int i = 0; i < 4; ++i) {
      int dq = (tid & 3) + 4 * i;
      float4 va = *reinterpret_cast<const float4*>(s0 + i * 16);
      float4 vc = *reinterpret_cast<const float4*>(s0 + i * 16 + 64);
      int t2 = 4 * tp;
      const float* fa = (const float*)&va;
      const float* fc = (const float*)&vc;
      #pragma unroll
      for (int jj = 0; jj < 4; ++jj) {
        int d = dq * 4 + jj;
        int addr = d * 512 + (t2 ^ ((d & 31) << 4));
        *reinterpret_cast<unsigned*>(smem + addr) = cvtpk(fa[jj] * ru, fc[jj] * ru);
      }
    }
  }

  // ---- Q B-frags: Q[qrow][dh] * CQ, bf16 ----
  const float* qrow = q + ((size_t)bhi * T_TOK + (size_t)u * 128 + w * 32 + ln) * 64;
  bf16x8 qf[4];
  #pragma unroll
  for (int sl = 0; sl < 4; ++sl) {
    float4 a4 = *reinterpret_cast<const float4*>(qrow + sl * 16 + lhi * 8);
    float4 b4 = *reinterpret_cast<const float4*>(qrow + sl * 16 + lhi * 8 + 4);
    union { unsigned uu[4]; bf16x8 f; } qu;
    qu.uu[0] = cvtpk(a4.x * CQ, a4.y * CQ);
    qu.uu[1] = cvtpk(a4.z * CQ, a4.w * CQ);
    qu.uu[2] = cvtpk(b4.x * CQ, b4.y * CQ);
    qu.uu[3] = cvtpk(b4.z * CQ, b4.w * CQ);
    qf[sl] = qu.f;
  }

  __syncthreads();  // VT complete

  // ---- main loop: 8 token-tiles of 32; fixed-shift softmax; PV per tile ----
  f32x16 o0, o1;
  #pragma unroll
  for (int r = 0; r < 16; ++r) { o0[r] = 0.f; o1[r] = 0.f; }
  float lsum = 0.f;  // per-lane: q-row ln, this lane's token subset

  #pragma unroll
  for (int t8 = 0; t8 < 8; ++t8) {
    int bucket = (t8 < 4) ? vu : u;
    const float* krow = kb + ((size_t)(bucket * 128 + (t8 & 3) * 32 + ln)) * 64 + lhi * 8;

    // QK^T tile: S^T[tok 32][qrow 32], K direct from global as A-frags
    f32x16 acc;
    #pragma unroll
    for (int r = 0; r < 16; ++r) acc[r] = 0.f;
    #pragma unroll
    for (int sl = 0; sl < 4; ++sl) {
      float4 f0 = *reinterpret_cast<const float4*>(krow + sl * 16);
      float4 f1 = *reinterpret_cast<const float4*>(krow + sl * 16 + 4);
      union { unsigned uu[4]; bf16x8 f; } kf;
      kf.uu[0] = cvtpk(f0.x, f0.y);
      kf.uu[1] = cvtpk(f0.z, f0.w);
      kf.uu[2] = cvtpk(f1.x, f1.y);
      kf.uu[3] = cvtpk(f1.z, f1.w);
      acc = __builtin_amdgcn_mfma_f32_32x32x16_bf16(kf.f, qf[sl], acc, 0, 0, 0);
    }

    // fixed-shift exp2: P = exp2(logit2 - M). vu-half logits scaled by ru.
    #pragma unroll
    for (int r = 0; r < 16; ++r) {
      float lg = (t8 < 4) ? acc[r] * ru : acc[r];
      float p = exp2v(lg - FIXED_M);
      acc[r] = p;
      lsum += p;
    }

    // P -> bf16 A-frags (cvt_pk + permlane32_swap); O = P @ V_cat (round-2 form)
    #pragma unroll
    for (int ks = 0; ks < 2; ++ks) {
      int r0 = 8 * ks;
      unsigned aA, bA, aB, bB;
      asm("v_cvt_pk_bf16_f32 %0, %1, %2" : "=v"(aA) : "v"(acc[r0 + 0]), "v"(acc[r0 + 1]));
      asm("v_cvt_pk_bf16_f32 %0, %1, %2" : "=v"(bA) : "v"(acc[r0 + 2]), "v"(acc[r0 + 3]));
      asm("v_cvt_pk_bf16_f32 %0, %1, %2" : "=v"(aB) : "v"(acc[r0 + 4]), "v"(acc[r0 + 5]));
      asm("v_cvt_pk_bf16_f32 %0, %1, %2" : "=v"(bB) : "v"(acc[r0 + 6]), "v"(acc[r0 + 7]));
      asm("s_nop 1\n\tv_permlane32_swap_b32 %0, %1\n\ts_nop 1" : "+v"(aA), "+v"(aB));
      asm("s_nop 1\n\tv_permlane32_swap_b32 %0, %1\n\ts_nop 1" : "+v"(bA), "+v"(bB));
      union { unsigned uu[4]; bf16x8 f; } pf;
      pf.uu[0] = aA; pf.uu[1] = bA; pf.uu[2] = aB; pf.uu[3] = bB;

      int t2 = 2 * (t8 * 32 + ks * 16 + lhi * 8);
      {
        int d = ln;
        int addr = d * 512 + (t2 ^ ((d & 31) << 4));
        bf16x8 vf = *reinterpret_cast<const bf16x8*>(smem + addr);
        o0 = __builtin_amdgcn_mfma_f32_32x32x16_bf16(pf.f, vf, o0, 0, 0, 0);
      }
      {
        int d = 32 + ln;
        int addr = d * 512 + (t2 ^ ((d & 31) << 4));
        bf16x8 vf = *reinterpret_cast<const bf16x8*>(smem + addr);
        o1 = __builtin_amdgcn_mfma_f32_32x32x16_bf16(pf.f, vf, o1, 0, 0, 0);
      }
    }
  }

  // ---- epilogue: combine lsum across half-pair; distribute inv per q-row ----
  // O layout (round-2 proven): o0[r] = O[qrow=crow(r,lhi)][d=ln], o1: d=32+ln.
  lsum += __shfl_xor(lsum, 32, 64);
  float inv = 1.f / lsum;  // valid for q-row ln (lanes ln and ln+32 agree)
  float* ob = out + ((size_t)bhi * T_TOK + (size_t)u * 128 + w * 32) * 64;
  #pragma unroll
  for (int r = 0; r < 16; ++r) {
    int row = (r & 3) + 8 * (r >> 2) + 4 * lhi;
    float invr = __shfl(inv, row, 64);  // lane 'row' holds q-row 'row''s inv
    ob[(size_t)row * 64 + ln] = o0[r] * invr;
    ob[(size_t)row * 64 + 32 + ln] = o1[r] * invr;
  }
}

extern "C" void kernel_launch(void* const* d_in, const int* in_sizes, int n_in,
                              void* d_out, int out_size, void* d_ws, size_t ws_size,
                              hipStream_t stream) {
  const float* q = (const float*)d_in[0];
  const float* k = (const float*)d_in[1];
  const float* v = (const float*)d_in[2];
  const float* W = (const float*)d_in[3];
  float* out = (float*)d_out;

  float* x = (float*)d_ws;  // 32*64*128 f32 = 1 MB

  hipLaunchKernelGGL(k1_sums, dim3(2048), dim3(128), 0, stream, q, k, x);
  hipLaunchKernelGGL(k3_attn, dim3(2048), dim3(256), 0, stream, q, k, v, x, W, out);
}

// Round 7
// 131.188 us; speedup vs baseline: 1.3747x; 1.3747x over previous
//
#include <hip/hip_runtime.h>

// SinkhornAttention: b=4,h=8,t=8192,dh=64, BUCKETS=64, bucket size 128.
// k1: bucket sums -> x[bh][64][128]
// k3: fused sortnet (per-wave, redundant) + bucketed attention.
//     PROVEN round-2 MFMA dataflow: S^T = mfma(K_afrag, Q_bfrag);
//     P->bf16 via cvt_pk+permlane32_swap; O = mfma(P_afrag, VT_bfrag).
//     Fixed-shift softmax (exact by shift invariance): no O rescaling.
//     LAUNCH BOUNDS: (256,2). (256,4) capped unified VGPR+AGPR at 128 and
//     spilled f32x16 state to scratch -> +220 MiB HBM traffic, 2.2x slowdown
//     (round-6 counters: WRITE_SIZE 196 MiB vs 64 MiB output).

#define T_TOK 8192
// 512^-0.5 * log2(e): fold into Q so logits land in exp2 domain.
#define CQ (0.04419417382415922f * 1.4426950408889634f)
#define FIXED_M 12.0f

typedef __attribute__((ext_vector_type(16))) float f32x16;
typedef __attribute__((ext_vector_type(8))) short bf16x8;

__device__ __forceinline__ unsigned cvtpk(float lo, float hi) {
  unsigned r;
  asm("v_cvt_pk_bf16_f32 %0, %1, %2" : "=v"(r) : "v"(lo), "v"(hi));
  return r;
}
__device__ __forceinline__ float exp2v(float x) {
  float r;
  asm("v_exp_f32 %0, %1\n\ts_nop 0" : "=v"(r) : "v"(x));
  return r;
}

// ---------------- Kernel 1: bucket summaries ----------------
__global__ __launch_bounds__(128) void k1_sums(const float* __restrict__ q,
                                               const float* __restrict__ k,
                                               float* __restrict__ x) {
  int G = blockIdx.x;
  int bhi = G >> 6, u = G & 63;
  int tid = threadIdx.x;
  const float* src = (tid < 64) ? q : k;
  int d = tid & 63;
  const float* p = src + ((size_t)bhi * T_TOK + (size_t)u * 128) * 64 + d;
  float s = 0.f;
  #pragma unroll 8
  for (int t = 0; t < 128; ++t) s += p[(size_t)t * 64];
  x[(size_t)G * 128 + tid] = s;
}

// ---------------- Kernel 3: fused sortnet + bucketed attention ----------------
// grid 2048, block 256 (4 waves). Wave w owns Q rows [32w,32w+32).
// LDS 32KB: VT = V_cat^T bf16 [64 d][256 tok], addr = d*512 + ((2*tok)^((d&31)<<4)).
//   toks 0..127 = ru*V[vu], toks 128..255 = V[u].
__global__ __launch_bounds__(256, 2) void k3_attn(
    const float* __restrict__ q, const float* __restrict__ k,
    const float* __restrict__ v, const float* __restrict__ x,
    const float* __restrict__ W, float* __restrict__ out) {
  __shared__ unsigned char smem[32768];

  int L = blockIdx.x;
  int G = ((L & 7) << 8) | (L >> 3);  // XCD swizzle (2048 % 8 == 0)
  int bhi = G >> 6, u = G & 63;
  int tid = threadIdx.x;
  int l = tid & 63;
  int w = tid >> 6;
  int lhi = l >> 5;
  int ln = l & 31;
  int hh = bhi & 7;

  const float* kb = k + (size_t)bhi * (T_TOK * 64);
  const float* vb = v + (size_t)bhi * (T_TOK * 64);

  // ---- stage V-own -> VT toks 128..255 (no dependency on sortnet) ----
  int tp = tid >> 2;  // 0..63 token-pair
  {
    const float* s0 = vb + ((size_t)(u * 128 + 2 * tp)) * 64 + (tid & 3) * 4;
    #pragma unroll
    for (int i = 0; i < 4; ++i) {
      int dq = (tid & 3) + 4 * i;
      float4 va = *reinterpret_cast<const float4*>(s0 + i * 16);
      float4 vc = *reinterpret_cast<const float4*>(s0 + i * 16 + 64);
      int t2 = 256 + 4 * tp;  // 2*(128 + 2*tp)
      const float* fa = (const float*)&va;
      const float* fc = (const float*)&vc;
      #pragma unroll
      for (int jj = 0; jj < 4; ++jj) {
        int d = dq * 4 + jj;
        int addr = d * 512 + (t2 ^ ((d & 31) << 4));
        *reinterpret_cast<unsigned*>(smem + addr) = cvtpk(fa[jj], fc[jj]);
      }
    }
  }

  // ---- sortnet, per-wave redundant: lane = candidate bucket v ----
  // fmaf over kk ascending: bitwise-identical to the validated k2 chain.
  const float* xrow = x + (size_t)bhi * 8192 + u * 128;
  const float* wcol = W + (size_t)hh * 8192 + l;
  float a = 0.f;
  #pragma unroll 8
  for (int kk = 0; kk < 128; ++kk) a = fmaf(xrow[kk], wcol[(size_t)kk * 64], a);
  a = fmaxf(a, 0.f);
  float bv = a; int bi = l;
  #pragma unroll
  for (int off = 1; off < 64; off <<= 1) {
    float ov = __shfl_xor(bv, off, 64);
    int oi = __shfl_xor(bi, off, 64);
    if (ov > bv || (ov == bv && oi < bi)) { bv = ov; bi = oi; }
  }
  float e = __expf(a - bv);
  #pragma unroll
  for (int off = 1; off < 64; off <<= 1) e += __shfl_xor(e, off, 64);
  int vu = bi;          // identical across wave
  float ru = 1.f / e;   // softmax value at argmax

  // ---- stage V-vu (scaled by ru) -> VT toks 0..127 ----
  {
    const float* s0 = vb + ((size_t)(vu * 128 + 2 * tp)) * 64 + (tid & 3) * 4;
    #pragma unroll
    for (int i = 0; i < 4; ++i) {
      int dq = (tid & 3) + 4 * i;
      float4 va = *reinterpret_cast<const float4*>(s0 + i * 16);
      float4 vc = *reinterpret_cast<const float4*>(s0 + i * 16 + 64);
      int t2 = 4 * tp;
      const float* fa = (const float*)&va;
      const float* fc = (const float*)&vc;
      #pragma unroll
      for (int jj = 0; jj < 4; ++jj) {
        int d = dq * 4 + jj;
        int addr = d * 512 + (t2 ^ ((d & 31) << 4));
        *reinterpret_cast<unsigned*>(smem + addr) = cvtpk(fa[jj] * ru, fc[jj] * ru);
      }
    }
  }

  // ---- Q B-frags: Q[qrow][dh] * CQ, bf16 ----
  const float* qrow = q + ((size_t)bhi * T_TOK + (size_t)u * 128 + w * 32 + ln) * 64;
  bf16x8 qf[4];
  #pragma unroll
  for (int sl = 0; sl < 4; ++sl) {
    float4 a4 = *reinterpret_cast<const float4*>(qrow + sl * 16 + lhi * 8);
    float4 b4 = *reinterpret_cast<const float4*>(qrow + sl * 16 + lhi * 8 + 4);
    union { unsigned uu[4]; bf16x8 f; } qu;
    qu.uu[0] = cvtpk(a4.x * CQ, a4.y * CQ);
    qu.uu[1] = cvtpk(a4.z * CQ, a4.w * CQ);
    qu.uu[2] = cvtpk(b4.x * CQ, b4.y * CQ);
    qu.uu[3] = cvtpk(b4.z * CQ, b4.w * CQ);
    qf[sl] = qu.f;
  }

  __syncthreads();  // VT complete

  // ---- main loop: 8 token-tiles of 32; fixed-shift softmax; PV per tile ----
  f32x16 o0, o1;
  #pragma unroll
  for (int r = 0; r < 16; ++r) { o0[r] = 0.f; o1[r] = 0.f; }
  float lsum = 0.f;  // per-lane: q-row ln, this lane's token subset

  #pragma unroll
  for (int t8 = 0; t8 < 8; ++t8) {
    int bucket = (t8 < 4) ? vu : u;
    const float* krow = kb + ((size_t)(bucket * 128 + (t8 & 3) * 32 + ln)) * 64 + lhi * 8;

    // QK^T tile: S^T[tok 32][qrow 32], K direct from global as A-frags
    f32x16 acc;
    #pragma unroll
    for (int r = 0; r < 16; ++r) acc[r] = 0.f;
    #pragma unroll
    for (int sl = 0; sl < 4; ++sl) {
      float4 f0 = *reinterpret_cast<const float4*>(krow + sl * 16);
      float4 f1 = *reinterpret_cast<const float4*>(krow + sl * 16 + 4);
      union { unsigned uu[4]; bf16x8 f; } kf;
      kf.uu[0] = cvtpk(f0.x, f0.y);
      kf.uu[1] = cvtpk(f0.z, f0.w);
      kf.uu[2] = cvtpk(f1.x, f1.y);
      kf.uu[3] = cvtpk(f1.z, f1.w);
      acc = __builtin_amdgcn_mfma_f32_32x32x16_bf16(kf.f, qf[sl], acc, 0, 0, 0);
    }

    // fixed-shift exp2: P = exp2(logit2 - M). vu-half logits scaled by ru.
    #pragma unroll
    for (int r = 0; r < 16; ++r) {
      float lg = (t8 < 4) ? acc[r] * ru : acc[r];
      float p = exp2v(lg - FIXED_M);
      acc[r] = p;
      lsum += p;
    }

    // P -> bf16 A-frags (cvt_pk + permlane32_swap); O = P @ V_cat (round-2 form)
    #pragma unroll
    for (int ks = 0; ks < 2; ++ks) {
      int r0 = 8 * ks;
      unsigned aA, bA, aB, bB;
      asm("v_cvt_pk_bf16_f32 %0, %1, %2" : "=v"(aA) : "v"(acc[r0 + 0]), "v"(acc[r0 + 1]));
      asm("v_cvt_pk_bf16_f32 %0, %1, %2" : "=v"(bA) : "v"(acc[r0 + 2]), "v"(acc[r0 + 3]));
      asm("v_cvt_pk_bf16_f32 %0, %1, %2" : "=v"(aB) : "v"(acc[r0 + 4]), "v"(acc[r0 + 5]));
      asm("v_cvt_pk_bf16_f32 %0, %1, %2" : "=v"(bB) : "v"(acc[r0 + 6]), "v"(acc[r0 + 7]));
      asm("s_nop 1\n\tv_permlane32_swap_b32 %0, %1\n\ts_nop 1" : "+v"(aA), "+v"(aB));
      asm("s_nop 1\n\tv_permlane32_swap_b32 %0, %1\n\ts_nop 1" : "+v"(bA), "+v"(bB));
      union { unsigned uu[4]; bf16x8 f; } pf;
      pf.uu[0] = aA; pf.uu[1] = bA; pf.uu[2] = aB; pf.uu[3] = bB;

      int t2 = 2 * (t8 * 32 + ks * 16 + lhi * 8);
      {
        int d = ln;
        int addr = d * 512 + (t2 ^ ((d & 31) << 4));
        bf16x8 vf = *reinterpret_cast<const bf16x8*>(smem + addr);
        o0 = __builtin_amdgcn_mfma_f32_32x32x16_bf16(pf.f, vf, o0, 0, 0, 0);
      }
      {
        int d = 32 + ln;
        int addr = d * 512 + (t2 ^ ((d & 31) << 4));
        bf16x8 vf = *reinterpret_cast<const bf16x8*>(smem + addr);
        o1 = __builtin_amdgcn_mfma_f32_32x32x16_bf16(pf.f, vf, o1, 0, 0, 0);
      }
    }
  }

  // ---- epilogue: combine lsum across half-pair; distribute inv per q-row ----
  // O layout (round-2 proven): o0[r] = O[qrow=crow(r,lhi)][d=ln], o1: d=32+ln.
  lsum += __shfl_xor(lsum, 32, 64);
  float inv = 1.f / lsum;  // valid for q-row ln (lanes ln and ln+32 agree)
  float* ob = out + ((size_t)bhi * T_TOK + (size_t)u * 128 + w * 32) * 64;
  #pragma unroll
  for (int r = 0; r < 16; ++r) {
    int row = (r & 3) + 8 * (r >> 2) + 4 * lhi;
    float invr = __shfl(inv, row, 64);  // lane 'row' holds q-row 'row''s inv
    ob[(size_t)row * 64 + ln] = o0[r] * invr;
    ob[(size_t)row * 64 + 32 + ln] = o1[r] * invr;
  }
}

extern "C" void kernel_launch(void* const* d_in, const int* in_sizes, int n_in,
                              void* d_out, int out_size, void* d_ws, size_t ws_size,
                              hipStream_t stream) {
  const float* q = (const float*)d_in[0];
  const float* k = (const float*)d_in[1];
  const float* v = (const float*)d_in[2];
  const float* W = (const float*)d_in[3];
  float* out = (float*)d_out;

  float* x = (float*)d_ws;  // 32*64*128 f32 = 1 MB

  hipLaunchKernelGGL(k1_sums, dim3(2048), dim3(128), 0, stream, q, k, x);
  hipLaunchKernelGGL(k3_attn, dim3(2048), dim3(256), 0, stream, q, k, v, x, W, out);
}

// Round 8
// 79.290 us; speedup vs baseline: 2.2744x; 1.6545x over previous
//
#include <hip/hip_runtime.h>

// SinkhornAttention: b=4,h=8,t=8192,dh=64, BUCKETS=64, bucket size 128.
// SINGLE fused kernel: bucket sums (own bucket only!) + sortnet + attention.
// Insight: block (bhi,u) needs only x[bhi][u][:] = [sum q[u]; sum k[u]],
// computed from data the block already loads (Q frags, K-own staging).
// Round-2-proven MFMA dataflow: S^T = mfma(K_afrag, Q_bfrag), P via
// cvt_pk+permlane32_swap, O = mfma(P_afrag, VT_bfrag). Fixed-shift softmax.
// K staged in LDS via bulk bursts (round-7 lesson: K-from-global inside the
// loop + serial sortnet destroyed memory-level parallelism -> 1.28 TB/s).

#define T_TOK 8192
// 512^-0.5 * log2(e): fold into Q so logits land in exp2 domain.
#define CQ (0.04419417382415922f * 1.4426950408889634f)
#define FIXED_M 12.0f

// LDS layout (71168 B total -> 2 blocks/CU):
#define KB_OFF 0       // 32 KB: K_cat bf16 [256 tok][64 d], byte ^((row&7)<<4)
#define VT_OFF 65536   // placeholder redefined below
#undef VT_OFF
#define VT_OFF 32768   // 32 KB: V^T bf16 [64 d][256 tok], byte ^((d&31)<<4)
#define XB_OFF 65536   // 512 B: x[128] f32 (q-sums 0..63, k-sums 64..127)
#define QP_OFF 66048   // 1 KB: qpart[4 waves][64 d]
#define KP_OFF 67072   // 4 KB: kpart[256 threads] float4

typedef __attribute__((ext_vector_type(16))) float f32x16;
typedef __attribute__((ext_vector_type(8))) short bf16x8;

__device__ __forceinline__ unsigned cvtpk(float lo, float hi) {
  unsigned r;
  asm("v_cvt_pk_bf16_f32 %0, %1, %2" : "=v"(r) : "v"(lo), "v"(hi));
  return r;
}
__device__ __forceinline__ float exp2v(float x) {
  float r;
  asm("v_exp_f32 %0, %1\n\ts_nop 0" : "=v"(r) : "v"(x));
  return r;
}

// grid 2048, block 256 (4 waves). Wave w owns Q rows [32w,32w+32).
__global__ __launch_bounds__(256, 2) void k3_attn(
    const float* __restrict__ q, const float* __restrict__ k,
    const float* __restrict__ v, const float* __restrict__ W,
    float* __restrict__ out) {
  __shared__ unsigned char smem[71168];

  int L = blockIdx.x;
  int G = ((L & 7) << 8) | (L >> 3);  // XCD swizzle (2048 % 8 == 0)
  int bhi = G >> 6, u = G & 63;
  int tid = threadIdx.x;
  int l = tid & 63;
  int w = tid >> 6;
  int lhi = l >> 5;
  int ln = l & 31;
  int hh = bhi & 7;

  const float* kb = k + (size_t)bhi * (T_TOK * 64);
  const float* vb = v + (size_t)bhi * (T_TOK * 64);

  // ---- Q loads: build frags AND keep raw f32 for bucket q-sums ----
  const float* qrow = q + ((size_t)bhi * T_TOK + (size_t)u * 128 + w * 32 + ln) * 64;
  bf16x8 qf[4];
  float qs[32];
  #pragma unroll
  for (int sl = 0; sl < 4; ++sl) {
    float4 a4 = *reinterpret_cast<const float4*>(qrow + sl * 16 + lhi * 8);
    float4 b4 = *reinterpret_cast<const float4*>(qrow + sl * 16 + lhi * 8 + 4);
    qs[sl * 8 + 0] = a4.x; qs[sl * 8 + 1] = a4.y;
    qs[sl * 8 + 2] = a4.z; qs[sl * 8 + 3] = a4.w;
    qs[sl * 8 + 4] = b4.x; qs[sl * 8 + 5] = b4.y;
    qs[sl * 8 + 6] = b4.z; qs[sl * 8 + 7] = b4.w;
    union { unsigned uu[4]; bf16x8 f; } qu;
    qu.uu[0] = cvtpk(a4.x * CQ, a4.y * CQ);
    qu.uu[1] = cvtpk(a4.z * CQ, a4.w * CQ);
    qu.uu[2] = cvtpk(b4.x * CQ, b4.y * CQ);
    qu.uu[3] = cvtpk(b4.z * CQ, b4.w * CQ);
    qf[sl] = qu.f;
  }
  // q-sums: reduce over the 32 rows held by this wave-half (offsets < 32
  // keep lhi halves separate; each half covers all 32 rows, its 32 cols)
  #pragma unroll
  for (int off = 1; off < 32; off <<= 1) {
    #pragma unroll
    for (int j = 0; j < 32; ++j) qs[j] += __shfl_xor(qs[j], off, 64);
  }
  if (ln == 0) {  // lanes 0 and 32 of each wave write their column set
    float* qp = (float*)(smem + QP_OFF) + w * 64 + lhi * 8;
    #pragma unroll
    for (int sl = 0; sl < 4; ++sl) {
      #pragma unroll
      for (int j = 0; j < 8; ++j) qp[sl * 16 + j] = qs[sl * 8 + j];
    }
  }

  // ---- K-own -> KB rows 128..255 (burst), accumulate k-sums ----
  int c4 = tid & 15;
  float4 ksum = make_float4(0.f, 0.f, 0.f, 0.f);
  #pragma unroll
  for (int it = 0; it < 8; ++it) {
    int row = (tid >> 4) + it * 16;  // 0..127
    float4 val = *reinterpret_cast<const float4*>(
        kb + (size_t)(u * 128 + row) * 64 + c4 * 4);
    ksum.x += val.x; ksum.y += val.y; ksum.z += val.z; ksum.w += val.w;
    int lr = 128 + row;
    int addr = KB_OFF + lr * 128 + ((c4 * 8) ^ ((lr & 7) << 4));
    *reinterpret_cast<uint2*>(smem + addr) =
        make_uint2(cvtpk(val.x, val.y), cvtpk(val.z, val.w));
  }
  *reinterpret_cast<float4*>(smem + KP_OFF + tid * 16) = ksum;

  // ---- V-own -> VT toks 128..255 (unscaled; independent of sortnet) ----
  int tp = tid >> 2;  // 0..63 token-pair
  {
    const float* s0 = vb + ((size_t)(u * 128 + 2 * tp)) * 64 + (tid & 3) * 4;
    #pragma unroll
    for (int i = 0; i < 4; ++i) {
      int dq = (tid & 3) + 4 * i;
      float4 va = *reinterpret_cast<const float4*>(s0 + i * 16);
      float4 vc = *reinterpret_cast<const float4*>(s0 + i * 16 + 64);
      int t2 = 256 + 4 * tp;
      const float* fa = (const float*)&va;
      const float* fc = (const float*)&vc;
      #pragma unroll
      for (int jj = 0; jj < 4; ++jj) {
        int d = dq * 4 + jj;
        int addr = VT_OFF + d * 512 + (t2 ^ ((d & 31) << 4));
        *reinterpret_cast<unsigned*>(smem + addr) = cvtpk(fa[jj], fc[jj]);
      }
    }
  }

  __syncthreads();  // B1: partial sums + own staging visible

  // ---- x reduce: 64 threads produce x[0..127] ----
  if (tid < 64) {
    const float* qp = (const float*)(smem + QP_OFF);
    float xq = qp[tid] + qp[64 + tid] + qp[128 + tid] + qp[192 + tid];
    const float* kp = (const float*)(smem + KP_OFF);
    float xk = 0.f;
    #pragma unroll
    for (int g = 0; g < 16; ++g) xk += kp[(g * 16 + (tid >> 2)) * 4 + (tid & 3)];
    float* xbw = (float*)(smem + XB_OFF);
    xbw[tid] = xq;
    xbw[64 + tid] = xk;
  }
  __syncthreads();  // B2: x visible

  // ---- sortnet, per-wave redundant: lane = candidate bucket v ----
  const float* xb = (const float*)(smem + XB_OFF);
  const float* wcol = W + (size_t)hh * 8192 + l;
  float a = 0.f;
  #pragma unroll 8
  for (int kk = 0; kk < 128; ++kk) a = fmaf(xb[kk], wcol[(size_t)kk * 64], a);
  a = fmaxf(a, 0.f);
  float bvv = a; int bi = l;
  #pragma unroll
  for (int off = 1; off < 64; off <<= 1) {
    float ov = __shfl_xor(bvv, off, 64);
    int oi = __shfl_xor(bi, off, 64);
    if (ov > bvv || (ov == bvv && oi < bi)) { bvv = ov; bi = oi; }
  }
  float e = __expf(a - bvv);
  #pragma unroll
  for (int off = 1; off < 64; off <<= 1) e += __shfl_xor(e, off, 64);
  int vu = bi;          // identical across wave
  float ru = 1.f / e;   // softmax value at argmax

  // ---- K[vu] -> KB rows 0..127 (burst) ----
  #pragma unroll
  for (int it = 0; it < 8; ++it) {
    int row = (tid >> 4) + it * 16;
    float4 val = *reinterpret_cast<const float4*>(
        kb + (size_t)(vu * 128 + row) * 64 + c4 * 4);
    int addr = KB_OFF + row * 128 + ((c4 * 8) ^ ((row & 7) << 4));
    *reinterpret_cast<uint2*>(smem + addr) =
        make_uint2(cvtpk(val.x, val.y), cvtpk(val.z, val.w));
  }

  // ---- V[vu] * ru -> VT toks 0..127 ----
  {
    const float* s0 = vb + ((size_t)(vu * 128 + 2 * tp)) * 64 + (tid & 3) * 4;
    #pragma unroll
    for (int i = 0; i < 4; ++i) {
      int dq = (tid & 3) + 4 * i;
      float4 va = *reinterpret_cast<const float4*>(s0 + i * 16);
      float4 vc = *reinterpret_cast<const float4*>(s0 + i * 16 + 64);
      int t2 = 4 * tp;
      const float* fa = (const float*)&va;
      const float* fc = (const float*)&vc;
      #pragma unroll
      for (int jj = 0; jj < 4; ++jj) {
        int d = dq * 4 + jj;
        int addr = VT_OFF + d * 512 + (t2 ^ ((d & 31) << 4));
        *reinterpret_cast<unsigned*>(smem + addr) = cvtpk(fa[jj] * ru, fc[jj] * ru);
      }
    }
  }

  __syncthreads();  // B3: full K_cat / VT visible

  // ---- main loop: 8 token-tiles; fixed-shift softmax; PV per tile ----
  f32x16 o0, o1;
  #pragma unroll
  for (int r = 0; r < 16; ++r) { o0[r] = 0.f; o1[r] = 0.f; }
  float lsum = 0.f;

  #pragma unroll
  for (int t8 = 0; t8 < 8; ++t8) {
    int tokr = t8 * 32 + ln;

    // QK^T tile: S^T[tok 32][qrow 32], K A-frags from LDS (swizzled b128)
    f32x16 acc;
    #pragma unroll
    for (int r = 0; r < 16; ++r) acc[r] = 0.f;
    #pragma unroll
    for (int sl = 0; sl < 4; ++sl) {
      int addr = KB_OFF + tokr * 128 + ((sl * 32 + lhi * 16) ^ ((tokr & 7) << 4));
      bf16x8 af = *reinterpret_cast<const bf16x8*>(smem + addr);
      acc = __builtin_amdgcn_mfma_f32_32x32x16_bf16(af, qf[sl], acc, 0, 0, 0);
    }

    // fixed-shift exp2: P = exp2(logit2 - M). vu-half logits scaled by ru.
    #pragma unroll
    for (int r = 0; r < 16; ++r) {
      float lg = (t8 < 4) ? acc[r] * ru : acc[r];
      float p = exp2v(lg - FIXED_M);
      acc[r] = p;
      lsum += p;
    }

    // P -> bf16 A-frags (cvt_pk + permlane32_swap); O = P @ V_cat
    #pragma unroll
    for (int ks = 0; ks < 2; ++ks) {
      int r0 = 8 * ks;
      unsigned aA, bA, aB, bB;
      asm("v_cvt_pk_bf16_f32 %0, %1, %2" : "=v"(aA) : "v"(acc[r0 + 0]), "v"(acc[r0 + 1]));
      asm("v_cvt_pk_bf16_f32 %0, %1, %2" : "=v"(bA) : "v"(acc[r0 + 2]), "v"(acc[r0 + 3]));
      asm("v_cvt_pk_bf16_f32 %0, %1, %2" : "=v"(aB) : "v"(acc[r0 + 4]), "v"(acc[r0 + 5]));
      asm("v_cvt_pk_bf16_f32 %0, %1, %2" : "=v"(bB) : "v"(acc[r0 + 6]), "v"(acc[r0 + 7]));
      asm("s_nop 1\n\tv_permlane32_swap_b32 %0, %1\n\ts_nop 1" : "+v"(aA), "+v"(aB));
      asm("s_nop 1\n\tv_permlane32_swap_b32 %0, %1\n\ts_nop 1" : "+v"(bA), "+v"(bB));
      union { unsigned uu[4]; bf16x8 f; } pf;
      pf.uu[0] = aA; pf.uu[1] = bA; pf.uu[2] = aB; pf.uu[3] = bB;

      int t2 = 2 * (t8 * 32 + ks * 16 + lhi * 8);
      {
        int d = ln;
        int addr = VT_OFF + d * 512 + (t2 ^ ((d & 31) << 4));
        bf16x8 vf = *reinterpret_cast<const bf16x8*>(smem + addr);
        o0 = __builtin_amdgcn_mfma_f32_32x32x16_bf16(pf.f, vf, o0, 0, 0, 0);
      }
      {
        int d = 32 + ln;
        int addr = VT_OFF + d * 512 + (t2 ^ ((d & 31) << 4));
        bf16x8 vf = *reinterpret_cast<const bf16x8*>(smem + addr);
        o1 = __builtin_amdgcn_mfma_f32_32x32x16_bf16(pf.f, vf, o1, 0, 0, 0);
      }
    }
  }

  // ---- epilogue: combine lsum across half-pair; distribute inv per q-row ----
  lsum += __shfl_xor(lsum, 32, 64);
  float inv = 1.f / lsum;
  float* ob = out + ((size_t)bhi * T_TOK + (size_t)u * 128 + w * 32) * 64;
  #pragma unroll
  for (int r = 0; r < 16; ++r) {
    int row = (r & 3) + 8 * (r >> 2) + 4 * lhi;
    float invr = __shfl(inv, row, 64);
    ob[(size_t)row * 64 + ln] = o0[r] * invr;
    ob[(size_t)row * 64 + 32 + ln] = o1[r] * invr;
  }
}

extern "C" void kernel_launch(void* const* d_in, const int* in_sizes, int n_in,
                              void* d_out, int out_size, void* d_ws, size_t ws_size,
                              hipStream_t stream) {
  const float* q = (const float*)d_in[0];
  const float* k = (const float*)d_in[1];
  const float* v = (const float*)d_in[2];
  const float* W = (const float*)d_in[3];
  float* out = (float*)d_out;

  hipLaunchKernelGGL(k3_attn, dim3(2048), dim3(256), 0, stream, q, k, v, W, out);
}

// Round 9
// 77.553 us; speedup vs baseline: 2.3254x; 1.0224x over previous
//
#include <hip/hip_runtime.h>

// SinkhornAttention: b=4,h=8,t=8192,dh=64, BUCKETS=64, bucket size 128.
// SINGLE fused kernel: bucket sums (own bucket only) + sortnet + attention.
// Round-2-proven MFMA dataflow: S^T = mfma(K_afrag, Q_bfrag), P via
// cvt_pk+permlane32_swap, O = mfma(P_afrag, VT_bfrag). Fixed-shift softmax.
// Round-9: T14 async-STAGE split -- K[vu]/V[vu] global loads issued into
// registers right after sortnet, own-half tiles (t8=4..7) computed while
// the loads are in flight, then convert+write LDS, barrier, vu-half tiles.

#define T_TOK 8192
// 512^-0.5 * log2(e): fold into Q so logits land in exp2 domain.
#define CQ (0.04419417382415922f * 1.4426950408889634f)
#define FIXED_M 12.0f

// LDS layout (71168 B total -> 2 blocks/CU):
#define KB_OFF 0       // 32 KB: K_cat bf16 [256 tok][64 d], byte ^((row&7)<<4)
#define VT_OFF 32768   // 32 KB: V^T bf16 [64 d][256 tok], byte ^((d&31)<<4)
#define XB_OFF 65536   // 512 B: x[128] f32 (q-sums 0..63, k-sums 64..127)
#define QP_OFF 66048   // 1 KB: qpart[4 waves][64 d]
#define KP_OFF 67072   // 4 KB: kpart[256 threads] float4

typedef __attribute__((ext_vector_type(16))) float f32x16;
typedef __attribute__((ext_vector_type(8))) short bf16x8;

__device__ __forceinline__ unsigned cvtpk(float lo, float hi) {
  unsigned r;
  asm("v_cvt_pk_bf16_f32 %0, %1, %2" : "=v"(r) : "v"(lo), "v"(hi));
  return r;
}
__device__ __forceinline__ float exp2v(float x) {
  float r;
  asm("v_exp_f32 %0, %1\n\ts_nop 0" : "=v"(r) : "v"(x));
  return r;
}

// One 32-token attention tile: QK^T from KB, fixed-shift exp2, P->bf16, PV.
#define ATTN_TILE(T8, VUHALF)                                                  \
  {                                                                            \
    int tokr = (T8) * 32 + ln;                                                 \
    f32x16 acc;                                                                \
    _Pragma("unroll") for (int r = 0; r < 16; ++r) acc[r] = 0.f;               \
    _Pragma("unroll") for (int sl = 0; sl < 4; ++sl) {                         \
      int addr =                                                               \
          KB_OFF + tokr * 128 + ((sl * 32 + lhi * 16) ^ ((tokr & 7) << 4));    \
      bf16x8 af = *reinterpret_cast<const bf16x8*>(smem + addr);               \
      acc = __builtin_amdgcn_mfma_f32_32x32x16_bf16(af, qf[sl], acc, 0, 0, 0); \
    }                                                                          \
    _Pragma("unroll") for (int r = 0; r < 16; ++r) {                           \
      float lg = (VUHALF) ? acc[r] * ru : acc[r];                              \
      float p = exp2v(lg - FIXED_M);                                           \
      acc[r] = p;                                                              \
      lsum += p;                                                               \
    }                                                                          \
    _Pragma("unroll") for (int ks = 0; ks < 2; ++ks) {                         \
      int r0 = 8 * ks;                                                         \
      unsigned aA, bA, aB, bB;                                                 \
      asm("v_cvt_pk_bf16_f32 %0, %1, %2"                                       \
          : "=v"(aA) : "v"(acc[r0 + 0]), "v"(acc[r0 + 1]));                    \
      asm("v_cvt_pk_bf16_f32 %0, %1, %2"                                       \
          : "=v"(bA) : "v"(acc[r0 + 2]), "v"(acc[r0 + 3]));                    \
      asm("v_cvt_pk_bf16_f32 %0, %1, %2"                                       \
          : "=v"(aB) : "v"(acc[r0 + 4]), "v"(acc[r0 + 5]));                    \
      asm("v_cvt_pk_bf16_f32 %0, %1, %2"                                       \
          : "=v"(bB) : "v"(acc[r0 + 6]), "v"(acc[r0 + 7]));                    \
      asm("s_nop 1\n\tv_permlane32_swap_b32 %0, %1\n\ts_nop 1"                 \
          : "+v"(aA), "+v"(aB));                                               \
      asm("s_nop 1\n\tv_permlane32_swap_b32 %0, %1\n\ts_nop 1"                 \
          : "+v"(bA), "+v"(bB));                                               \
      union { unsigned uu[4]; bf16x8 f; } pf;                                  \
      pf.uu[0] = aA; pf.uu[1] = bA; pf.uu[2] = aB; pf.uu[3] = bB;              \
      int t2 = 2 * ((T8) * 32 + ks * 16 + lhi * 8);                            \
      {                                                                        \
        int d = ln;                                                            \
        int addr = VT_OFF + d * 512 + (t2 ^ ((d & 31) << 4));                  \
        bf16x8 vf = *reinterpret_cast<const bf16x8*>(smem + addr);             \
        o0 = __builtin_amdgcn_mfma_f32_32x32x16_bf16(pf.f, vf, o0, 0, 0, 0);   \
      }                                                                        \
      {                                                                        \
        int d = 32 + ln;                                                       \
        int addr = VT_OFF + d * 512 + (t2 ^ ((d & 31) << 4));                  \
        bf16x8 vf = *reinterpret_cast<const bf16x8*>(smem + addr);             \
        o1 = __builtin_amdgcn_mfma_f32_32x32x16_bf16(pf.f, vf, o1, 0, 0, 0);   \
      }                                                                        \
    }                                                                          \
  }

// grid 2048, block 256 (4 waves). Wave w owns Q rows [32w,32w+32).
__global__ __launch_bounds__(256, 2) void k3_attn(
    const float* __restrict__ q, const float* __restrict__ k,
    const float* __restrict__ v, const float* __restrict__ W,
    float* __restrict__ out) {
  __shared__ unsigned char smem[71168];

  int L = blockIdx.x;
  int G = ((L & 7) << 8) | (L >> 3);  // XCD swizzle (2048 % 8 == 0)
  int bhi = G >> 6, u = G & 63;
  int tid = threadIdx.x;
  int l = tid & 63;
  int w = tid >> 6;
  int lhi = l >> 5;
  int ln = l & 31;
  int hh = bhi & 7;

  const float* kb = k + (size_t)bhi * (T_TOK * 64);
  const float* vb = v + (size_t)bhi * (T_TOK * 64);

  // ---- Q loads: build frags AND keep raw f32 for bucket q-sums ----
  const float* qrow = q + ((size_t)bhi * T_TOK + (size_t)u * 128 + w * 32 + ln) * 64;
  bf16x8 qf[4];
  float qs[32];
  #pragma unroll
  for (int sl = 0; sl < 4; ++sl) {
    float4 a4 = *reinterpret_cast<const float4*>(qrow + sl * 16 + lhi * 8);
    float4 b4 = *reinterpret_cast<const float4*>(qrow + sl * 16 + lhi * 8 + 4);
    qs[sl * 8 + 0] = a4.x; qs[sl * 8 + 1] = a4.y;
    qs[sl * 8 + 2] = a4.z; qs[sl * 8 + 3] = a4.w;
    qs[sl * 8 + 4] = b4.x; qs[sl * 8 + 5] = b4.y;
    qs[sl * 8 + 6] = b4.z; qs[sl * 8 + 7] = b4.w;
    union { unsigned uu[4]; bf16x8 f; } qu;
    qu.uu[0] = cvtpk(a4.x * CQ, a4.y * CQ);
    qu.uu[1] = cvtpk(a4.z * CQ, a4.w * CQ);
    qu.uu[2] = cvtpk(b4.x * CQ, b4.y * CQ);
    qu.uu[3] = cvtpk(b4.z * CQ, b4.w * CQ);
    qf[sl] = qu.f;
  }
  // q-sums: reduce over the 32 rows held by this wave (lhi halves separate)
  #pragma unroll
  for (int off = 1; off < 32; off <<= 1) {
    #pragma unroll
    for (int j = 0; j < 32; ++j) qs[j] += __shfl_xor(qs[j], off, 64);
  }
  if (ln == 0) {
    float* qp = (float*)(smem + QP_OFF) + w * 64 + lhi * 8;
    #pragma unroll
    for (int sl = 0; sl < 4; ++sl) {
      #pragma unroll
      for (int j = 0; j < 8; ++j) qp[sl * 16 + j] = qs[sl * 8 + j];
    }
  }

  // ---- K-own -> KB rows 128..255 (burst), accumulate k-sums ----
  int c4 = tid & 15;
  float4 ksum = make_float4(0.f, 0.f, 0.f, 0.f);
  #pragma unroll
  for (int it = 0; it < 8; ++it) {
    int row = (tid >> 4) + it * 16;  // 0..127
    float4 val = *reinterpret_cast<const float4*>(
        kb + (size_t)(u * 128 + row) * 64 + c4 * 4);
    ksum.x += val.x; ksum.y += val.y; ksum.z += val.z; ksum.w += val.w;
    int lr = 128 + row;
    int addr = KB_OFF + lr * 128 + ((c4 * 8) ^ ((lr & 7) << 4));
    *reinterpret_cast<uint2*>(smem + addr) =
        make_uint2(cvtpk(val.x, val.y), cvtpk(val.z, val.w));
  }
  *reinterpret_cast<float4*>(smem + KP_OFF + tid * 16) = ksum;

  // ---- V-own -> VT toks 128..255 (unscaled; independent of sortnet) ----
  int tp = tid >> 2;  // 0..63 token-pair
  {
    const float* s0 = vb + ((size_t)(u * 128 + 2 * tp)) * 64 + (tid & 3) * 4;
    #pragma unroll
    for (int i = 0; i < 4; ++i) {
      int dq = (tid & 3) + 4 * i;
      float4 va = *reinterpret_cast<const float4*>(s0 + i * 16);
      float4 vc = *reinterpret_cast<const float4*>(s0 + i * 16 + 64);
      int t2 = 256 + 4 * tp;
      const float* fa = (const float*)&va;
      const float* fc = (const float*)&vc;
      #pragma unroll
      for (int jj = 0; jj < 4; ++jj) {
        int d = dq * 4 + jj;
        int addr = VT_OFF + d * 512 + (t2 ^ ((d & 31) << 4));
        *reinterpret_cast<unsigned*>(smem + addr) = cvtpk(fa[jj], fc[jj]);
      }
    }
  }

  __syncthreads();  // B1: partial sums + own staging visible

  // ---- x reduce: 64 threads produce x[0..127] ----
  if (tid < 64) {
    const float* qp = (const float*)(smem + QP_OFF);
    float xq = qp[tid] + qp[64 + tid] + qp[128 + tid] + qp[192 + tid];
    const float* kp = (const float*)(smem + KP_OFF);
    float xk = 0.f;
    #pragma unroll
    for (int g = 0; g < 16; ++g) xk += kp[(g * 16 + (tid >> 2)) * 4 + (tid & 3)];
    float* xbw = (float*)(smem + XB_OFF);
    xbw[tid] = xq;
    xbw[64 + tid] = xk;
  }
  __syncthreads();  // B2: x visible

  // ---- sortnet, per-wave redundant: lane = candidate bucket v ----
  const float* xb = (const float*)(smem + XB_OFF);
  const float* wcol = W + (size_t)hh * 8192 + l;
  float a = 0.f;
  #pragma unroll 8
  for (int kk = 0; kk < 128; ++kk) a = fmaf(xb[kk], wcol[(size_t)kk * 64], a);
  a = fmaxf(a, 0.f);
  float bvv = a; int bi = l;
  #pragma unroll
  for (int off = 1; off < 64; off <<= 1) {
    float ov = __shfl_xor(bvv, off, 64);
    int oi = __shfl_xor(bi, off, 64);
    if (ov > bvv || (ov == bvv && oi < bi)) { bvv = ov; bi = oi; }
  }
  float e = __expf(a - bvv);
  #pragma unroll
  for (int off = 1; off < 64; off <<= 1) e += __shfl_xor(e, off, 64);
  int vu = bi;          // identical across wave
  float ru = 1.f / e;   // softmax value at argmax

  // ---- T14 async-STAGE: issue K[vu], V[vu] loads into registers NOW ----
  float4 kvu[8];
  #pragma unroll
  for (int it = 0; it < 8; ++it) {
    int row = (tid >> 4) + it * 16;
    kvu[it] = *reinterpret_cast<const float4*>(
        kb + (size_t)(vu * 128 + row) * 64 + c4 * 4);
  }
  float4 vvu[8];
  {
    const float* s0 = vb + ((size_t)(vu * 128 + 2 * tp)) * 64 + (tid & 3) * 4;
    #pragma unroll
    for (int i = 0; i < 4; ++i) {
      vvu[i] = *reinterpret_cast<const float4*>(s0 + i * 16);
      vvu[4 + i] = *reinterpret_cast<const float4*>(s0 + i * 16 + 64);
    }
  }

  // ---- own-half tiles (t8=4..7) while vu loads are in flight ----
  f32x16 o0, o1;
  #pragma unroll
  for (int r = 0; r < 16; ++r) { o0[r] = 0.f; o1[r] = 0.f; }
  float lsum = 0.f;

  #pragma unroll
  for (int t8 = 4; t8 < 8; ++t8) ATTN_TILE(t8, false)

  // ---- drain vu loads; convert+write to LDS (disjoint from own-half) ----
  #pragma unroll
  for (int it = 0; it < 8; ++it) {
    int row = (tid >> 4) + it * 16;
    int addr = KB_OFF + row * 128 + ((c4 * 8) ^ ((row & 7) << 4));
    *reinterpret_cast<uint2*>(smem + addr) =
        make_uint2(cvtpk(kvu[it].x, kvu[it].y), cvtpk(kvu[it].z, kvu[it].w));
  }
  #pragma unroll
  for (int i = 0; i < 4; ++i) {
    int dq = (tid & 3) + 4 * i;
    int t2 = 4 * tp;
    const float* fa = (const float*)&vvu[i];
    const float* fc = (const float*)&vvu[4 + i];
    #pragma unroll
    for (int jj = 0; jj < 4; ++jj) {
      int d = dq * 4 + jj;
      int addr = VT_OFF + d * 512 + (t2 ^ ((d & 31) << 4));
      *reinterpret_cast<unsigned*>(smem + addr) = cvtpk(fa[jj] * ru, fc[jj] * ru);
    }
  }
  __syncthreads();  // B3: vu halves visible

  // ---- vu-half tiles (t8=0..3) ----
  #pragma unroll
  for (int t8 = 0; t8 < 4; ++t8) ATTN_TILE(t8, true)

  // ---- epilogue: combine lsum across half-pair; distribute inv per q-row ----
  lsum += __shfl_xor(lsum, 32, 64);
  float inv = 1.f / lsum;
  float* ob = out + ((size_t)bhi * T_TOK + (size_t)u * 128 + w * 32) * 64;
  #pragma unroll
  for (int r = 0; r < 16; ++r) {
    int row = (r & 3) + 8 * (r >> 2) + 4 * lhi;
    float invr = __shfl(inv, row, 64);
    ob[(size_t)row * 64 + ln] = o0[r] * invr;
    ob[(size_t)row * 64 + 32 + ln] = o1[r] * invr;
  }
}

extern "C" void kernel_launch(void* const* d_in, const int* in_sizes, int n_in,
                              void* d_out, int out_size, void* d_ws, size_t ws_size,
                              hipStream_t stream) {
  const float* q = (const float*)d_in[0];
  const float* k = (const float*)d_in[1];
  const float* v = (const float*)d_in[2];
  const float* W = (const float*)d_in[3];
  float* out = (float*)d_out;

  hipLaunchKernelGGL(k3_attn, dim3(2048), dim3(256), 0, stream, q, k, v, W, out);
}